// Round 6
// baseline (18224.240 us; speedup 1.0000x reference)
//
#include <hip/hip_runtime.h>

#define NWIN 28
#define HALO_MAX 704

typedef short bf16x8 __attribute__((ext_vector_type(8)));
typedef float f32x4 __attribute__((ext_vector_type(4)));

struct WinG {
  int ti, li, hp, wp, dh, dw, oh, ow, to, lo;
  int TH, TW, cy, cx;
  int vbase, dbase, pbase, jbase, bbase;
};

struct Geo {
  WinG w[NWIN];
  int vtot, dtot, ptot, jtot, btot, maxhalo;
};

constexpr Geo make_geo() {
  Geo g{};
  int vb = 0, db = 0, pb = 0, jb = 0, bb = 0, mh = 0;
  int k = 0;
  for (int s = 0; s < 7; ++s) {
    double sv = (s == 6) ? 1.0 : (2.0 + (double)s * (-1.0 / 6.0));  // np.linspace(2,1,7), endpoint exact
    float sc = (float)sv;
    int a = 16 * s, b2 = 16 * (s + 1), c = 224 - b2, d = 224 - a;
    int rect[4][4] = {{a, a, b2, c}, {b2, a, d, b2}, {c, b2, d, d}, {a, c, c, d}};
    for (int q = 0; q < 4; ++q) {
      WinG wg{};
      wg.ti = rect[q][0]; wg.li = rect[q][1];
      int bi = rect[q][2], ri = rect[q][3];
      wg.oh = bi - wg.ti; wg.ow = ri - wg.li;
      wg.hp = wg.oh + 12; wg.wp = wg.ow + 12;
      wg.dh = (int)((float)wg.hp / sc);   // matches int(np.float32(hp)/scale)
      wg.dw = (int)((float)wg.wp / sc);
      wg.to = wg.ti; wg.lo = wg.li;
      // compile-time tile-shape search: minimize tiles, then maximize useful area
      int bestT = 1 << 30, bTH = 16, bTW = 16, bA = 0;
      for (int TH = 1; TH <= 128; ++TH) {
        for (int TW = 8; TW <= 256; ++TW) {
          if (TH * TW > 256) break;
          if ((TH + 6) * (TW + 6) > HALO_MAX) continue;
          int cy = (wg.dh + TH - 1) / TH, cx = (wg.dw + TW - 1) / TW;
          int tiles = cy * cx, area = TH * TW;
          if (tiles < bestT || (tiles == bestT && area > bA)) { bestT = tiles; bTH = TH; bTW = TW; bA = area; }
        }
      }
      wg.TH = bTH; wg.TW = bTW;
      wg.cy = (wg.dh + bTH - 1) / bTH; wg.cx = (wg.dw + bTW - 1) / bTW;
      int halo = (bTH + 6) * (bTW + 6);
      if (halo > mh) mh = halo;
      wg.vbase = vb; wg.dbase = db; wg.pbase = pb; wg.jbase = jb; wg.bbase = bb;
      vb += wg.dh * wg.wp; db += wg.dh * wg.dw; pb += (wg.oh / 2) * (wg.ow / 2);
      jb += wg.dh; bb += wg.cy * wg.cx * 16;
      g.w[k++] = wg;
    }
  }
  g.vtot = vb; g.dtot = db; g.ptot = pb; g.jtot = jb; g.btot = bb; g.maxhalo = mh;
  return g;
}

static constexpr Geo GEO = make_geo();
static_assert(GEO.ptot == 12544, "pooled px must tile 112x112");
static_assert(GEO.dtot <= GEO.vtot, "cw must fit in vtmp region");
static_assert((long long)GEO.dtot * 1024 <= 51380224LL, "ds must fit in x region");
static_assert(GEO.maxhalo <= HALO_MAX, "halo budget");

#define XELEMS 51380224   // 16*64*224*224
#define POOL_N 12845056   // 16*64*112*112
#define WB_UINTS 114688   // 8cc*14s*4ct*64lane*4 uints (bf16 B-fragments)

// ---- weight transposes: wt[ic][tap][oc] = wconv[oc][ic][tap]; wfbT[ic][oc] = wfb[oc][ic] ----
__global__ __launch_bounds__(256) void k_wtr(const float* __restrict__ wc, const float* __restrict__ wfb,
                                             float* __restrict__ wt, float* __restrict__ wfbT) {
  int e = blockIdx.x * 256 + threadIdx.x;
  if (e < 200704) {
    int oc = e & 63, r = e >> 6;
    int t = r % 49, ic = r / 49;
    wt[e] = wc[(oc * 64 + ic) * 49 + t];
  } else if (e < 200704 + 8192) {
    int e2 = e - 200704;
    int oc = e2 & 63, ic = e2 >> 6;      // ic in [0,128)
    wfbT[e2] = wfb[oc * 128 + ic];
  }
}

// ---- B-fragment prepack for MFMA probe: wb[cc][s][ct][lane] = 8 bf16 (4 uints) ----
// k within an ic-chunk: k = s*32 + (lane>>4)*8 + j ; ic8 = k/56, t = k%56 (t>=49 zero-padded)
__global__ __launch_bounds__(256) void k_wpack(const float* __restrict__ wc, unsigned* __restrict__ wb) {
  int e = blockIdx.x * 256 + threadIdx.x;
  if (e >= WB_UINTS) return;
  int j2 = e & 3;
  int r = e >> 2;
  int lane = r & 63; r >>= 6;
  int ct = r & 3; r >>= 2;           // r = cc*14 + s
  int s = r % 14, cc = r / 14;
  int oc = ct * 16 + (lane & 15);
  int g = lane >> 4;
  unsigned out = 0;
#pragma unroll
  for (int h = 0; h < 2; ++h) {
    int j = j2 * 2 + h;
    int k = s * 32 + g * 8 + j;
    int ic8 = k / 56, t = k - ic8 * 56;
    unsigned b16 = 0;
    if (t < 49) {
      unsigned bits = __float_as_uint(wc[(oc * 64 + cc * 8 + ic8) * 49 + t]);
      b16 = (bits + 0x7FFFu + ((bits >> 16) & 1u)) >> 16;   // RN to bf16
    }
    out |= b16 << (16 * h);
  }
  wb[e] = out;
}

// ---- 1x1 conv: x[n][oc][hw] = sum_ic wfbT[ic][oc]*cat(f,b); weights via uniform (scalar) loads ----
__global__ __launch_bounds__(256) void k_pointwise(const float* __restrict__ f, const float* __restrict__ b,
                                                   const float* __restrict__ wfbT, float* __restrict__ x) {
  int p = blockIdx.x * 256 + threadIdx.x;
  int n = p / 50176, hw = p - n * 50176;
  const float* fp = f + (size_t)n * 64 * 50176 + hw;
  const float* bp = b + (size_t)n * 64 * 50176 + hw;
  float acc[64];
#pragma unroll
  for (int i = 0; i < 64; ++i) acc[i] = 0.f;
#pragma unroll 2
  for (int ic = 0; ic < 64; ++ic) {
    float v = fp[(size_t)ic * 50176];
    const float4* wr = (const float4*)(wfbT + ic * 64);   // uniform address -> s_load
#pragma unroll
    for (int o = 0; o < 16; ++o) {
      float4 ww = wr[o];
      acc[4 * o + 0] = fmaf(ww.x, v, acc[4 * o + 0]);
      acc[4 * o + 1] = fmaf(ww.y, v, acc[4 * o + 1]);
      acc[4 * o + 2] = fmaf(ww.z, v, acc[4 * o + 2]);
      acc[4 * o + 3] = fmaf(ww.w, v, acc[4 * o + 3]);
    }
  }
#pragma unroll 2
  for (int ic = 0; ic < 64; ++ic) {
    float v = bp[(size_t)ic * 50176];
    const float4* wr = (const float4*)(wfbT + (64 + ic) * 64);
#pragma unroll
    for (int o = 0; o < 16; ++o) {
      float4 ww = wr[o];
      acc[4 * o + 0] = fmaf(ww.x, v, acc[4 * o + 0]);
      acc[4 * o + 1] = fmaf(ww.y, v, acc[4 * o + 1]);
      acc[4 * o + 2] = fmaf(ww.z, v, acc[4 * o + 2]);
      acc[4 * o + 3] = fmaf(ww.w, v, acc[4 * o + 3]);
    }
  }
  float* xo = x + (size_t)n * 64 * 50176 + hw;
#pragma unroll
  for (int oc = 0; oc < 64; ++oc) xo[(size_t)oc * 50176] = acc[oc];
}

// ---- vertical antialias resize (block = (win, n, out-row j)) ----
__global__ __launch_bounds__(256) void k_vresize(const float* __restrict__ x, float* __restrict__ vtmp) {
  int bid = blockIdx.x;
  int w = 0;
#pragma unroll
  for (int i = 1; i < NWIN; ++i) if (bid >= GEO.w[i].jbase * 16) w = i;
  const WinG& wg = GEO.w[w];
  int rem = bid - wg.jbase * 16;
  int n = rem / wg.dh;
  int j = rem - n * wg.dh;

  float invf = (float)(1.0 / ((double)wg.dh / (double)wg.hp));  // f32(1/scale), like JAX
  float ks = fmaxf(invf, 1.0f);
  float sample = ((float)j + 0.5f) * invf - 0.5f;
  int i0 = (int)ceilf(sample - ks);
  int i1 = (int)floorf(sample + ks);
  if (i0 < 0) i0 = 0;
  if (i1 > wg.hp - 1) i1 = wg.hp - 1;
  int nt = i1 - i0 + 1;  // <=5
  float wts[5]; int rowoff[5]; bool rok[5];
  float tot = 0.f;
  for (int t = 0; t < nt; ++t) {
    float xx = fabsf(sample - (float)(i0 + t)) / ks;
    float wgt = fmaxf(0.f, 1.f - xx);
    wts[t] = wgt; tot += wgt;
  }
  for (int t = 0; t < nt; ++t) {
    wts[t] = wts[t] / tot;             // JAX normalizes then dots
    int xr = wg.ti - 6 + i0 + t;       // padded-window row -> image row
    rok[t] = ((unsigned)xr < 224u);
    rowoff[t] = xr * 224;
  }
  int P = wg.wp <= 32 ? 32 : wg.wp <= 64 ? 64 : wg.wp <= 128 ? 128 : 256;
  int lgP = wg.wp <= 32 ? 5 : wg.wp <= 64 ? 6 : wg.wp <= 128 ? 7 : 8;
  int col = threadIdx.x & (P - 1);
  int cg = threadIdx.x >> lgP;
  int G = 256 >> lgP;
  const float* xn = x + (size_t)n * 64 * 50176;
  float* vout = vtmp + (size_t)wg.vbase * 1024 + (size_t)n * 64 * wg.dh * wg.wp + (size_t)j * wg.wp;
  for (int c0 = col; c0 < wg.wp; c0 += P) {
    int xc = wg.li - 6 + c0;
    bool cok = ((unsigned)xc < 224u);
    for (int c = cg; c < 64; c += G) {
      const float* xp_ = xn + (size_t)c * 50176 + xc;
      float a = 0.f;
      for (int t = 0; t < nt; ++t)
        if (rok[t] & cok) a = fmaf(wts[t], xp_[rowoff[t]], a);
      vout[(size_t)c * wg.dh * wg.wp + c0] = a;
    }
  }
}

// ---- horizontal antialias resize ----
__global__ __launch_bounds__(256) void k_hresize(const float* __restrict__ vtmp, float* __restrict__ ds) {
  int bid = blockIdx.x;
  int w = 0;
#pragma unroll
  for (int i = 1; i < NWIN; ++i) if (bid >= GEO.w[i].jbase * 16) w = i;
  const WinG& wg = GEO.w[w];
  int rem = bid - wg.jbase * 16;
  int n = rem / wg.dh;
  int j = rem - n * wg.dh;

  int P2 = wg.dw <= 32 ? 32 : wg.dw <= 64 ? 64 : 128;
  int lgP = wg.dw <= 32 ? 5 : wg.dw <= 64 ? 6 : 7;
  int i = threadIdx.x & (P2 - 1);
  int cg = threadIdx.x >> lgP;
  int G = 256 >> lgP;
  if (i >= wg.dw) return;

  float invf = (float)(1.0 / ((double)wg.dw / (double)wg.wp));
  float ks = fmaxf(invf, 1.0f);
  float sample = ((float)i + 0.5f) * invf - 0.5f;
  int i0 = (int)ceilf(sample - ks);
  int i1 = (int)floorf(sample + ks);
  if (i0 < 0) i0 = 0;
  if (i1 > wg.wp - 1) i1 = wg.wp - 1;
  int nt = i1 - i0 + 1;
  float wts[5]; int off[5];
  float tot = 0.f;
#pragma unroll
  for (int t = 0; t < 5; ++t) {
    float xx = fabsf(sample - (float)(i0 + t)) / ks;
    float wgt = (t < nt) ? fmaxf(0.f, 1.f - xx) : 0.f;
    wts[t] = wgt; tot += wgt;
    off[t] = i0 + ((t < nt) ? t : 0);  // clamped index; weight 0 beyond nt
  }
#pragma unroll
  for (int t = 0; t < 5; ++t) wts[t] = wts[t] / tot;

  const float* vin = vtmp + (size_t)wg.vbase * 1024 + (size_t)n * 64 * wg.dh * wg.wp + (size_t)j * wg.wp;
  float* dso = ds + (size_t)wg.dbase * 1024 + (size_t)n * 64 * wg.dh * wg.dw + (size_t)j * wg.dw;
  for (int c = cg; c < 64; c += G) {
    const float* vp = vin + (size_t)c * wg.dh * wg.wp;
    float a = 0.f;
#pragma unroll
    for (int t = 0; t < 5; ++t) a = fmaf(wts[t], vp[off[t]], a);
    dso[(size_t)c * wg.dh * wg.dw + i] = a;
  }
}

// ---- 7x7 SAME conv 64ic->64oc: input in LDS (dbuf by 8-ic chunk), weights via scalar loads ----
__global__ __launch_bounds__(256) void k_conv(const float* __restrict__ ds, const float* __restrict__ wt,
                                              float* __restrict__ cw) {
  __shared__ float sIn[2][8 * HALO_MAX];
  int bid = blockIdx.x;
  int w = 0;
#pragma unroll
  for (int i = 1; i < NWIN; ++i) if (bid >= GEO.w[i].bbase) w = i;
  const WinG& wg = GEO.w[w];
  int rem = bid - wg.bbase;
  int tiles = wg.cy * wg.cx;
  int n = rem / tiles;
  int t = rem - n * tiles;
  int ty = t / wg.cx, tx = t - ty * wg.cx;
  const int TH = wg.TH, TW = wg.TW, dh = wg.dh, dw = wg.dw;
  const int W6 = TW + 6, halo = (TH + 6) * W6;
  int y0 = ty * TH, x0 = tx * TW;
  const float* dsw = ds + (size_t)wg.dbase * 1024 + (size_t)n * 64 * dh * dw;
  float* cww = cw + (size_t)wg.dbase * 1024 + (size_t)n * 64 * dh * dw;
  const int tid = threadIdx.x;
  int yl = tid / TW;
  int xl = tid - yl * TW;
  if (yl > TH - 1) yl = TH - 1;  // spare lanes duplicate a valid px (benign)

  float acc[64];
#pragma unroll
  for (int i2 = 0; i2 < 64; ++i2) acc[i2] = 0.f;

  auto stage = [&](int icc, int buf) {
    for (int e = tid; e < 8 * halo; e += 256) {
      int ic8 = e / halo; int r = e - ic8 * halo;
      int yy = r / W6; int xx = r - yy * W6;
      int gy = y0 + yy - 3, gx = x0 + xx - 3;
      float v = 0.f;
      if ((unsigned)gy < (unsigned)dh && (unsigned)gx < (unsigned)dw)
        v = dsw[(((size_t)icc * 8 + ic8) * dh + gy) * dw + gx];
      sIn[buf][e] = v;
    }
  };

  stage(0, 0);
  __syncthreads();

#pragma unroll 1
  for (int icc = 0; icc < 8; ++icc) {
    int ibuf = icc & 1;
    if (icc < 7) stage(icc + 1, ibuf ^ 1);
#pragma unroll 1
    for (int ic8 = 0; ic8 < 8; ++ic8) {
      const float* inp = &sIn[ibuf][ic8 * halo];
      const float4* wq = (const float4*)(wt + (size_t)(icc * 8 + ic8) * 3136);  // uniform -> s_load
#pragma unroll 1
      for (int ky = 0; ky < 7; ++ky) {
        const float* inr = inp + (yl + ky) * W6 + xl;
        const float4* wrow = wq + ky * 7 * 16;
#pragma unroll
        for (int kx = 0; kx < 7; ++kx) {
          float v = inr[kx];
          const float4* w4 = wrow + kx * 16;
#pragma unroll
          for (int o = 0; o < 16; ++o) {
            float4 ww = w4[o];
            acc[4 * o + 0] = fmaf(ww.x, v, acc[4 * o + 0]);
            acc[4 * o + 1] = fmaf(ww.y, v, acc[4 * o + 1]);
            acc[4 * o + 2] = fmaf(ww.z, v, acc[4 * o + 2]);
            acc[4 * o + 3] = fmaf(ww.w, v, acc[4 * o + 3]);
          }
        }
      }
    }
    __syncthreads();
  }
  int gy = y0 + yl, gx = x0 + xl;
  if (gy < dh && gx < dw) {
#pragma unroll
    for (int oc = 0; oc < 64; ++oc) cww[((size_t)oc * dh + gy) * dw + gx] = acc[oc];
  }
}

// ---- SHADOW PROBE: MFMA 7x7 conv (bf16), same tiling; reads dsb, writes back into dsb (dead region).
// Runs AFTER k_pool -> cannot affect outputs. Purpose: measure MFMA-conv time + counters.
__global__ __launch_bounds__(256) void k_conv_mfma(const float* __restrict__ ds, const uint4* __restrict__ wb,
                                                   float* __restrict__ outp) {
  __shared__ float sIn[2][8 * HALO_MAX];
  int bid = blockIdx.x;
  int w = 0;
#pragma unroll
  for (int i = 1; i < NWIN; ++i) if (bid >= GEO.w[i].bbase) w = i;
  const WinG& wg = GEO.w[w];
  int rem = bid - wg.bbase;
  int tiles = wg.cy * wg.cx;
  int n = rem / tiles;
  int t = rem - n * tiles;
  int ty = t / wg.cx, tx = t - ty * wg.cx;
  const int TH = wg.TH, TW = wg.TW, dh = wg.dh, dw = wg.dw;
  const int W6 = TW + 6, halo = (TH + 6) * W6;
  int y0 = ty * TH, x0 = tx * TW;
  const float* dsw = ds + (size_t)wg.dbase * 1024 + (size_t)n * 64 * dh * dw;
  float* oww = outp + (size_t)wg.dbase * 1024 + (size_t)n * 64 * dh * dw;
  const int tid = threadIdx.x;

  auto stage = [&](int icc, int buf) {
    for (int e = tid; e < 8 * halo; e += 256) {
      int ic8 = e / halo; int r = e - ic8 * halo;
      int yy = r / W6; int xx = r - yy * W6;
      int gy = y0 + yy - 3, gx = x0 + xx - 3;
      float v = 0.f;
      if ((unsigned)gy < (unsigned)dh && (unsigned)gx < (unsigned)dw)
        v = dsw[(((size_t)icc * 8 + ic8) * dh + gy) * dw + gx];
      sIn[buf][e] = v;
    }
  };

  int lane = tid & 63, wave = tid >> 6;
  int row = lane & 15, g = lane >> 4;
  // A-gather pixel coords per row-tile (clamped; writes are guarded)
  int pxy[4], pxx[4];
#pragma unroll
  for (int rt = 0; rt < 4; ++rt) {
    int px = wave * 64 + rt * 16 + row;
    int mx = TH * TW - 1;
    if (px > mx) px = mx;
    pxy[rt] = px / TW; pxx[rt] = px - pxy[rt] * TW;
  }

  f32x4 acc[4][4];
#pragma unroll
  for (int i1 = 0; i1 < 4; ++i1)
#pragma unroll
    for (int i2 = 0; i2 < 4; ++i2)
#pragma unroll
      for (int i3 = 0; i3 < 4; ++i3) acc[i1][i2][i3] = 0.f;

  stage(0, 0);
  __syncthreads();

#pragma unroll 1
  for (int cc = 0; cc < 8; ++cc) {
    int ibuf = cc & 1;
    if (cc < 7) stage(cc + 1, ibuf ^ 1);
#pragma unroll 1
    for (int s = 0; s < 14; ++s) {
      int kk = s * 32 + g * 8;
      int ic8 = kk / 56;
      int t0 = kk - ic8 * 56;          // multiple of 8, <=48; t0..t0+7 never cross ic8
      const float* abase = &sIn[ibuf][ic8 * halo];
      bf16x8 af[4];
#pragma unroll
      for (int rt = 0; rt < 4; ++rt) {
        int pb = pxy[rt] * W6 + pxx[rt];
        unsigned aw[4];
#pragma unroll
        for (int j2 = 0; j2 < 4; ++j2) {
          unsigned lo = 0, hi = 0;
          int ta = t0 + 2 * j2;
          if (ta < 49) {
            unsigned bits = __float_as_uint(abase[pb + (ta / 7) * W6 + (ta % 7)]);
            lo = (bits + 0x7FFFu + ((bits >> 16) & 1u)) >> 16;
          }
          int tb = ta + 1;
          if (tb < 49) {
            unsigned bits = __float_as_uint(abase[pb + (tb / 7) * W6 + (tb % 7)]);
            hi = (bits + 0x7FFFu + ((bits >> 16) & 1u)) >> 16;
          }
          aw[j2] = lo | (hi << 16);
        }
        union { unsigned u[4]; bf16x8 v; } cv;
        cv.u[0] = aw[0]; cv.u[1] = aw[1]; cv.u[2] = aw[2]; cv.u[3] = aw[3];
        af[rt] = cv.v;
      }
      const uint4* wrow = wb + ((size_t)(cc * 14 + s) * 4) * 64 + lane;
      bf16x8 bfr[4];
#pragma unroll
      for (int ct = 0; ct < 4; ++ct) {
        union { uint4 q; bf16x8 v; } cb;
        cb.q = wrow[ct * 64];
        bfr[ct] = cb.v;
      }
#pragma unroll
      for (int rt = 0; rt < 4; ++rt)
#pragma unroll
        for (int ct = 0; ct < 4; ++ct)
          acc[rt][ct] = __builtin_amdgcn_mfma_f32_16x16x32_bf16(af[rt], bfr[ct], acc[rt][ct], 0, 0, 0);
    }
    __syncthreads();
  }

  // C layout: col = lane&15 (oc within tile), row = g*4 + reg (px within 16-row tile)
#pragma unroll
  for (int rt = 0; rt < 4; ++rt) {
#pragma unroll
    for (int ct = 0; ct < 4; ++ct) {
      int oc = ct * 16 + row;
#pragma unroll
      for (int r4 = 0; r4 < 4; ++r4) {
        int px = wave * 64 + rt * 16 + g * 4 + r4;
        if (px < TH * TW) {
          int yl2 = px / TW, xl2 = px - yl2 * TW;
          int gy = y0 + yl2, gx = x0 + xl2;
          if (gy < dh && gx < dw)
            oww[((size_t)oc * dh + gy) * dw + gx] = acc[rt][ct][r4];
        }
      }
    }
  }
}

// ---- nearest upsample + relu + 2x2 maxpool(argmax); idx written as FLOAT values ----
__global__ __launch_bounds__(256) void k_pool(const float* __restrict__ cw, float* __restrict__ vals,
                                              float* __restrict__ idxo) {
  int e = blockIdx.x * 256 + threadIdx.x;
  int w = 0;
#pragma unroll
  for (int i = 1; i < NWIN; ++i) if (e >= GEO.w[i].pbase * 1024) w = i;
  const WinG& wg = GEO.w[w];
  int local = e - wg.pbase * 1024;
  int poh = wg.oh >> 1, pw = wg.ow >> 1;
  int pa = poh * pw;
  int nc = local / pa;
  int r2 = local - nc * pa;
  int pr = r2 / pw;
  int pc = r2 - pr * pw;
  const float* base = cw + (size_t)wg.dbase * 1024 + (size_t)nc * wg.dh * wg.dw;
  int h0 = 2 * pr, w0 = 2 * pc;
  int jd0 = (h0 * wg.dh) / wg.oh, jd1 = ((h0 + 1) * wg.dh) / wg.oh;
  int id0 = (w0 * wg.dw) / wg.ow, id1 = ((w0 + 1) * wg.dw) / wg.ow;
  float v00 = fmaxf(base[jd0 * wg.dw + id0], 0.f);
  float v01 = fmaxf(base[jd0 * wg.dw + id1], 0.f);
  float v10 = fmaxf(base[jd1 * wg.dw + id0], 0.f);
  float v11 = fmaxf(base[jd1 * wg.dw + id1], 0.f);
  float best = v00; int barg = 0;
  if (v01 > best) { best = v01; barg = 1; }
  if (v10 > best) { best = v10; barg = 2; }
  if (v11 > best) { best = v11; barg = 3; }
  int prg = (wg.to >> 1) + pr, pcg = (wg.lo >> 1) + pc;
  int out_i = (nc * 112 + prg) * 112 + pcg;
  vals[out_i] = best;
  int hh = 2 * prg + (barg >> 1), ww_ = 2 * pcg + (barg & 1);
  idxo[out_i] = (float)(hh * 224 + ww_);   // harness reads d_out as float32; write numeric value
}

extern "C" void kernel_launch(void* const* d_in, const int* in_sizes, int n_in,
                              void* d_out, int out_size, void* d_ws, size_t ws_size,
                              hipStream_t stream) {
  (void)in_sizes; (void)n_in; (void)out_size; (void)ws_size;
  const float* f = (const float*)d_in[0];
  const float* b = (const float*)d_in[1];
  const float* wfb = (const float*)d_in[2];
  const float* wconv = (const float*)d_in[3];
  float* ws = (float*)d_ws;

  float* xbuf = ws;                                    // region A: 51,380,224 floats
  float* vtmp = ws + XELEMS;                           // region B: vtot*1024 floats
  float* wt = ws + XELEMS + (size_t)GEO.vtot * 1024;   // 200,704 floats
  float* wfbT = wt + 200704;                           // 8,192 floats
  unsigned* wbp = (unsigned*)(wfbT + 8192);            // 114,688 uints (bf16 B-fragments)
  float* dsb = xbuf;                                   // reuse region A (x dead after vresize)
  float* cwb = vtmp;                                   // reuse region B (vtmp dead after hresize)
  float* vals = (float*)d_out;
  float* idxo = (float*)d_out + POOL_N;

  k_wtr<<<816, 256, 0, stream>>>(wconv, wfb, wt, wfbT);
  k_wpack<<<WB_UINTS / 256, 256, 0, stream>>>(wconv, wbp);
  k_pointwise<<<802816 / 256, 256, 0, stream>>>(f, b, wfbT, xbuf);
  k_vresize<<<GEO.jtot * 16, 256, 0, stream>>>(xbuf, vtmp);
  k_hresize<<<GEO.jtot * 16, 256, 0, stream>>>(vtmp, dsb);
  k_conv<<<GEO.btot, 256, 0, stream>>>(dsb, wt, cwb);
  k_pool<<<(GEO.ptot * 1024) / 256, 256, 0, stream>>>(cwb, vals, idxo);
  // shadow probe last: reads dsb (dead), writes into dsb region; outputs already final
  k_conv_mfma<<<GEO.btot, 256, 0, stream>>>(dsb, (const uint4*)wbp, dsb);
}

// Round 7
// 1558.584 us; speedup vs baseline: 11.6928x; 11.6928x over previous
//
#include <hip/hip_runtime.h>

#define NWIN 28
#define HALO_MAX 704

typedef short bf16x8 __attribute__((ext_vector_type(8)));
typedef float f32x4 __attribute__((ext_vector_type(4)));

struct WinG {
  int ti, li, hp, wp, dh, dw, oh, ow, to, lo;
  int TH, TW, cy, cx;
  int vbase, dbase, pbase, jbase, bbase;
};

struct Geo {
  WinG w[NWIN];
  int vtot, dtot, ptot, jtot, btot, maxhalo;
};

constexpr Geo make_geo() {
  Geo g{};
  int vb = 0, db = 0, pb = 0, jb = 0, bb = 0, mh = 0;
  int k = 0;
  for (int s = 0; s < 7; ++s) {
    double sv = (s == 6) ? 1.0 : (2.0 + (double)s * (-1.0 / 6.0));  // np.linspace(2,1,7), endpoint exact
    float sc = (float)sv;
    int a = 16 * s, b2 = 16 * (s + 1), c = 224 - b2, d = 224 - a;
    int rect[4][4] = {{a, a, b2, c}, {b2, a, d, b2}, {c, b2, d, d}, {a, c, c, d}};
    for (int q = 0; q < 4; ++q) {
      WinG wg{};
      wg.ti = rect[q][0]; wg.li = rect[q][1];
      int bi = rect[q][2], ri = rect[q][3];
      wg.oh = bi - wg.ti; wg.ow = ri - wg.li;
      wg.hp = wg.oh + 12; wg.wp = wg.ow + 12;
      wg.dh = (int)((float)wg.hp / sc);   // matches int(np.float32(hp)/scale)
      wg.dw = (int)((float)wg.wp / sc);
      wg.to = wg.ti; wg.lo = wg.li;
      // compile-time tile-shape search: minimize tiles, then maximize useful area
      int bestT = 1 << 30, bTH = 16, bTW = 16, bA = 0;
      for (int TH = 1; TH <= 128; ++TH) {
        for (int TW = 8; TW <= 256; ++TW) {
          if (TH * TW > 256) break;
          if ((TH + 6) * (TW + 6) > HALO_MAX) continue;
          int cy = (wg.dh + TH - 1) / TH, cx = (wg.dw + TW - 1) / TW;
          int tiles = cy * cx, area = TH * TW;
          if (tiles < bestT || (tiles == bestT && area > bA)) { bestT = tiles; bTH = TH; bTW = TW; bA = area; }
        }
      }
      wg.TH = bTH; wg.TW = bTW;
      wg.cy = (wg.dh + bTH - 1) / bTH; wg.cx = (wg.dw + bTW - 1) / bTW;
      int halo = (bTH + 6) * (bTW + 6);
      if (halo > mh) mh = halo;
      wg.vbase = vb; wg.dbase = db; wg.pbase = pb; wg.jbase = jb; wg.bbase = bb;
      vb += wg.dh * wg.wp; db += wg.dh * wg.dw; pb += (wg.oh / 2) * (wg.ow / 2);
      jb += wg.dh; bb += wg.cy * wg.cx * 16;
      g.w[k++] = wg;
    }
  }
  g.vtot = vb; g.dtot = db; g.ptot = pb; g.jtot = jb; g.btot = bb; g.maxhalo = mh;
  return g;
}

static constexpr Geo GEO = make_geo();
static_assert(GEO.ptot == 12544, "pooled px must tile 112x112");
static_assert(GEO.dtot <= GEO.vtot, "cw must fit in vtmp region");
static_assert((long long)GEO.dtot * 1024 <= 51380224LL, "ds must fit in x region");
static_assert(GEO.maxhalo <= HALO_MAX, "halo budget");

#define XELEMS 51380224   // 16*64*224*224
#define POOL_N 12845056   // 16*64*112*112
#define WB2_UINTS 100352  // 2 s2 * 49 tap * 4 ct * 64 lane * 4 uints (bf16 B-fragments, k=ic)

// ---- weight transposes (wt now unused by conv; kept byte-identical — validated) ----
__global__ __launch_bounds__(256) void k_wtr(const float* __restrict__ wc, const float* __restrict__ wfb,
                                             float* __restrict__ wt, float* __restrict__ wfbT) {
  int e = blockIdx.x * 256 + threadIdx.x;
  if (e < 200704) {
    int oc = e & 63, r = e >> 6;
    int t = r % 49, ic = r / 49;
    wt[e] = wc[(oc * 64 + ic) * 49 + t];
  } else if (e < 200704 + 8192) {
    int e2 = e - 200704;
    int oc = e2 & 63, ic = e2 >> 6;      // ic in [0,128)
    wfbT[e2] = wfb[oc * 128 + ic];
  }
}

// ---- B-fragment prepack: wb[s2][tap][ct][lane] = 8 bf16 (uint4). k = ic within 32-block:
// ic = s2*32 + (lane>>4)*8 + j ; oc = ct*16 + (lane&15). Same k-placement rule as A (perm-invariant).
__global__ __launch_bounds__(256) void k_wpack(const float* __restrict__ wc, unsigned* __restrict__ wb) {
  int e = blockIdx.x * 256 + threadIdx.x;
  if (e >= WB2_UINTS) return;
  int j2 = e & 3;
  int r = e >> 2;
  int lane = r & 63; r >>= 6;
  int ct = r & 3; r >>= 2;           // r = s2*49 + tap
  int tap = r % 49, s2 = r / 49;
  int oc = ct * 16 + (lane & 15);
  int g = lane >> 4;
  unsigned out = 0;
#pragma unroll
  for (int h = 0; h < 2; ++h) {
    int j = j2 * 2 + h;
    int ic = s2 * 32 + g * 8 + j;
    unsigned bits = __float_as_uint(wc[(oc * 64 + ic) * 49 + tap]);
    unsigned b16 = (bits + 0x7FFFu + ((bits >> 16) & 1u)) >> 16;   // RNE to bf16
    out |= b16 << (16 * h);
  }
  wb[e] = out;
}

// ---- 1x1 conv (unchanged this round; known s_load-latency suspect — fix after measuring) ----
__global__ __launch_bounds__(256) void k_pointwise(const float* __restrict__ f, const float* __restrict__ b,
                                                   const float* __restrict__ wfbT, float* __restrict__ x) {
  int p = blockIdx.x * 256 + threadIdx.x;
  int n = p / 50176, hw = p - n * 50176;
  const float* fp = f + (size_t)n * 64 * 50176 + hw;
  const float* bp = b + (size_t)n * 64 * 50176 + hw;
  float acc[64];
#pragma unroll
  for (int i = 0; i < 64; ++i) acc[i] = 0.f;
#pragma unroll 2
  for (int ic = 0; ic < 64; ++ic) {
    float v = fp[(size_t)ic * 50176];
    const float4* wr = (const float4*)(wfbT + ic * 64);
#pragma unroll
    for (int o = 0; o < 16; ++o) {
      float4 ww = wr[o];
      acc[4 * o + 0] = fmaf(ww.x, v, acc[4 * o + 0]);
      acc[4 * o + 1] = fmaf(ww.y, v, acc[4 * o + 1]);
      acc[4 * o + 2] = fmaf(ww.z, v, acc[4 * o + 2]);
      acc[4 * o + 3] = fmaf(ww.w, v, acc[4 * o + 3]);
    }
  }
#pragma unroll 2
  for (int ic = 0; ic < 64; ++ic) {
    float v = bp[(size_t)ic * 50176];
    const float4* wr = (const float4*)(wfbT + (64 + ic) * 64);
#pragma unroll
    for (int o = 0; o < 16; ++o) {
      float4 ww = wr[o];
      acc[4 * o + 0] = fmaf(ww.x, v, acc[4 * o + 0]);
      acc[4 * o + 1] = fmaf(ww.y, v, acc[4 * o + 1]);
      acc[4 * o + 2] = fmaf(ww.z, v, acc[4 * o + 2]);
      acc[4 * o + 3] = fmaf(ww.w, v, acc[4 * o + 3]);
    }
  }
  float* xo = x + (size_t)n * 64 * 50176 + hw;
#pragma unroll
  for (int oc = 0; oc < 64; ++oc) xo[(size_t)oc * 50176] = acc[oc];
}

// ---- vertical antialias resize (unchanged, validated) ----
__global__ __launch_bounds__(256) void k_vresize(const float* __restrict__ x, float* __restrict__ vtmp) {
  int bid = blockIdx.x;
  int w = 0;
#pragma unroll
  for (int i = 1; i < NWIN; ++i) if (bid >= GEO.w[i].jbase * 16) w = i;
  const WinG& wg = GEO.w[w];
  int rem = bid - wg.jbase * 16;
  int n = rem / wg.dh;
  int j = rem - n * wg.dh;

  float invf = (float)(1.0 / ((double)wg.dh / (double)wg.hp));  // f32(1/scale), like JAX
  float ks = fmaxf(invf, 1.0f);
  float sample = ((float)j + 0.5f) * invf - 0.5f;
  int i0 = (int)ceilf(sample - ks);
  int i1 = (int)floorf(sample + ks);
  if (i0 < 0) i0 = 0;
  if (i1 > wg.hp - 1) i1 = wg.hp - 1;
  int nt = i1 - i0 + 1;  // <=5
  float wts[5]; int rowoff[5]; bool rok[5];
  float tot = 0.f;
  for (int t = 0; t < nt; ++t) {
    float xx = fabsf(sample - (float)(i0 + t)) / ks;
    float wgt = fmaxf(0.f, 1.f - xx);
    wts[t] = wgt; tot += wgt;
  }
  for (int t = 0; t < nt; ++t) {
    wts[t] = wts[t] / tot;             // JAX normalizes then dots
    int xr = wg.ti - 6 + i0 + t;       // padded-window row -> image row
    rok[t] = ((unsigned)xr < 224u);
    rowoff[t] = xr * 224;
  }
  int P = wg.wp <= 32 ? 32 : wg.wp <= 64 ? 64 : wg.wp <= 128 ? 128 : 256;
  int lgP = wg.wp <= 32 ? 5 : wg.wp <= 64 ? 6 : wg.wp <= 128 ? 7 : 8;
  int col = threadIdx.x & (P - 1);
  int cg = threadIdx.x >> lgP;
  int G = 256 >> lgP;
  const float* xn = x + (size_t)n * 64 * 50176;
  float* vout = vtmp + (size_t)wg.vbase * 1024 + (size_t)n * 64 * wg.dh * wg.wp + (size_t)j * wg.wp;
  for (int c0 = col; c0 < wg.wp; c0 += P) {
    int xc = wg.li - 6 + c0;
    bool cok = ((unsigned)xc < 224u);
    for (int c = cg; c < 64; c += G) {
      const float* xp_ = xn + (size_t)c * 50176 + xc;
      float a = 0.f;
      for (int t = 0; t < nt; ++t)
        if (rok[t] & cok) a = fmaf(wts[t], xp_[rowoff[t]], a);
      vout[(size_t)c * wg.dh * wg.wp + c0] = a;
    }
  }
}

// ---- horizontal antialias resize (unchanged, validated) ----
__global__ __launch_bounds__(256) void k_hresize(const float* __restrict__ vtmp, float* __restrict__ ds) {
  int bid = blockIdx.x;
  int w = 0;
#pragma unroll
  for (int i = 1; i < NWIN; ++i) if (bid >= GEO.w[i].jbase * 16) w = i;
  const WinG& wg = GEO.w[w];
  int rem = bid - wg.jbase * 16;
  int n = rem / wg.dh;
  int j = rem - n * wg.dh;

  int P2 = wg.dw <= 32 ? 32 : wg.dw <= 64 ? 64 : 128;
  int lgP = wg.dw <= 32 ? 5 : wg.dw <= 64 ? 6 : 7;
  int i = threadIdx.x & (P2 - 1);
  int cg = threadIdx.x >> lgP;
  int G = 256 >> lgP;
  if (i >= wg.dw) return;

  float invf = (float)(1.0 / ((double)wg.dw / (double)wg.wp));
  float ks = fmaxf(invf, 1.0f);
  float sample = ((float)i + 0.5f) * invf - 0.5f;
  int i0 = (int)ceilf(sample - ks);
  int i1 = (int)floorf(sample + ks);
  if (i0 < 0) i0 = 0;
  if (i1 > wg.wp - 1) i1 = wg.wp - 1;
  int nt = i1 - i0 + 1;
  float wts[5]; int off[5];
  float tot = 0.f;
#pragma unroll
  for (int t = 0; t < 5; ++t) {
    float xx = fabsf(sample - (float)(i0 + t)) / ks;
    float wgt = (t < nt) ? fmaxf(0.f, 1.f - xx) : 0.f;
    wts[t] = wgt; tot += wgt;
    off[t] = i0 + ((t < nt) ? t : 0);  // clamped index; weight 0 beyond nt
  }
#pragma unroll
  for (int t = 0; t < 5; ++t) wts[t] = wts[t] / tot;

  const float* vin = vtmp + (size_t)wg.vbase * 1024 + (size_t)n * 64 * wg.dh * wg.wp + (size_t)j * wg.wp;
  float* dso = ds + (size_t)wg.dbase * 1024 + (size_t)n * 64 * wg.dh * wg.dw + (size_t)j * wg.dw;
  for (int c = cg; c < 64; c += G) {
    const float* vp = vin + (size_t)c * wg.dh * wg.wp;
    float a = 0.f;
#pragma unroll
    for (int t = 0; t < 5; ++t) a = fmaf(wts[t], vp[off[t]], a);
    dso[(size_t)c * wg.dh * wg.dw + i] = a;
  }
}

// ---- 7x7 SAME conv via MFMA (bf16 in, fp32 acc). K over ic (32/MFMA, 2 steps); taps = 49 rounds.
// LDS: bf16 [g][cell][8ic] (one ds_read_b128 per A-fragment). B prepacked, coalesced, L2-hot.
// Wave = 64 px x 64 oc; 4 waves cover 256-px tile.
__global__ __launch_bounds__(256) void k_conv_mfma(const float* __restrict__ ds, const uint4* __restrict__ wb,
                                                   float* __restrict__ cw) {
  __shared__ uint4 sB[4 * HALO_MAX];   // 45,056 B: [g][cell] cells of 8 bf16
  int bid = blockIdx.x;
  int w = 0;
#pragma unroll
  for (int i = 1; i < NWIN; ++i) if (bid >= GEO.w[i].bbase) w = i;
  const WinG& wg = GEO.w[w];
  int rem = bid - wg.bbase;
  int tiles = wg.cy * wg.cx;
  int n = rem / tiles;
  int t = rem - n * tiles;
  int ty = t / wg.cx, tx = t - ty * wg.cx;
  const int TH = wg.TH, TW = wg.TW, dh = wg.dh, dw = wg.dw;
  const int W6 = TW + 6, halo = (TH + 6) * W6;
  int y0 = ty * TH, x0 = tx * TW;
  const float* dsw = ds + (size_t)wg.dbase * 1024 + (size_t)n * 64 * dh * dw;
  float* cww = cw + (size_t)wg.dbase * 1024 + (size_t)n * 64 * dh * dw;
  const int tid = threadIdx.x;
  int lane = tid & 63, wave = tid >> 6;
  int row = lane & 15, g = lane >> 4;

  // A-read base cell per row-tile (px clamped for reads; writes separately guarded)
  int rbase[4];
#pragma unroll
  for (int rt = 0; rt < 4; ++rt) {
    int px = wave * 64 + rt * 16 + row;
    int mx = TH * TW - 1;
    if (px > mx) px = mx;
    int py = px / TW, pxx = px - py * TW;
    rbase[rt] = g * HALO_MAX + py * W6 + pxx;
  }

  f32x4 acc[4][4];
#pragma unroll
  for (int i1 = 0; i1 < 4; ++i1)
#pragma unroll
    for (int i2 = 0; i2 < 4; ++i2)
#pragma unroll
      for (int i3 = 0; i3 < 4; ++i3) acc[i1][i2][i3] = 0.f;

  const size_t chs = (size_t)dh * dw;   // channel stride

#pragma unroll 1
  for (int s2 = 0; s2 < 2; ++s2) {
    if (s2) __syncthreads();   // all reads of previous ic-block done before overwrite
    // stage ic [s2*32, s2*32+32) as bf16 [g][cell][8]
    for (int e = tid; e < 4 * halo; e += 256) {
      int gg = e / halo, cell = e - gg * halo;
      int yy = cell / W6, xx = cell - yy * W6;
      int gy = y0 + yy - 3, gx = x0 + xx - 3;
      bool ok = ((unsigned)gy < (unsigned)dh) && ((unsigned)gx < (unsigned)dw);
      const float* src = dsw + (size_t)(s2 * 32 + gg * 8) * chs + (size_t)gy * dw + gx;
      unsigned pk[4];
#pragma unroll
      for (int j2 = 0; j2 < 4; ++j2) {
        unsigned lo = 0, hi = 0;
        if (ok) {
          unsigned b0 = __float_as_uint(src[(size_t)(2 * j2) * chs]);
          lo = (b0 + 0x7FFFu + ((b0 >> 16) & 1u)) >> 16;
          unsigned b1 = __float_as_uint(src[(size_t)(2 * j2 + 1) * chs]);
          hi = (b1 + 0x7FFFu + ((b1 >> 16) & 1u)) >> 16;
        }
        pk[j2] = lo | (hi << 16);
      }
      uint4 u; u.x = pk[0]; u.y = pk[1]; u.z = pk[2]; u.w = pk[3];
      sB[gg * HALO_MAX + cell] = u;
    }
    __syncthreads();

#pragma unroll 1
    for (int ky = 0; ky < 7; ++ky) {
#pragma unroll 1
      for (int kx = 0; kx < 7; ++kx) {
        int coff = ky * W6 + kx;
        bf16x8 af[4];
#pragma unroll
        for (int rt = 0; rt < 4; ++rt) {
          union { uint4 q; bf16x8 v; } ca;
          ca.q = sB[rbase[rt] + coff];
          af[rt] = ca.v;
        }
        const uint4* bq = wb + ((size_t)(s2 * 49 + ky * 7 + kx) * 4) * 64 + lane;
#pragma unroll
        for (int ct = 0; ct < 4; ++ct) {
          union { uint4 q; bf16x8 v; } cb;
          cb.q = bq[ct * 64];
#pragma unroll
          for (int rt = 0; rt < 4; ++rt)
            acc[rt][ct] = __builtin_amdgcn_mfma_f32_16x16x32_bf16(af[rt], cb.v, acc[rt][ct], 0, 0, 0);
        }
      }
    }
  }

  // C/D layout (m89-verified): col = lane&15 -> oc, row = g*4 + reg -> px-in-16-row-block
#pragma unroll
  for (int ct = 0; ct < 4; ++ct) {
    int oc = ct * 16 + row;
#pragma unroll
    for (int rt = 0; rt < 4; ++rt) {
#pragma unroll
      for (int r4 = 0; r4 < 4; ++r4) {
        int px = wave * 64 + rt * 16 + g * 4 + r4;
        if (px < TH * TW) {
          int yl2 = px / TW, xl2 = px - yl2 * TW;
          int gy = y0 + yl2, gx = x0 + xl2;
          if (gy < dh && gx < dw)
            cww[(size_t)oc * chs + (size_t)gy * dw + gx] = acc[rt][ct][r4];
        }
      }
    }
  }
}

// ---- nearest upsample + relu + 2x2 maxpool(argmax); idx as float (unchanged, validated) ----
__global__ __launch_bounds__(256) void k_pool(const float* __restrict__ cw, float* __restrict__ vals,
                                              float* __restrict__ idxo) {
  int e = blockIdx.x * 256 + threadIdx.x;
  int w = 0;
#pragma unroll
  for (int i = 1; i < NWIN; ++i) if (e >= GEO.w[i].pbase * 1024) w = i;
  const WinG& wg = GEO.w[w];
  int local = e - wg.pbase * 1024;
  int poh = wg.oh >> 1, pw = wg.ow >> 1;
  int pa = poh * pw;
  int nc = local / pa;
  int r2 = local - nc * pa;
  int pr = r2 / pw;
  int pc = r2 - pr * pw;
  const float* base = cw + (size_t)wg.dbase * 1024 + (size_t)nc * wg.dh * wg.dw;
  int h0 = 2 * pr, w0 = 2 * pc;
  int jd0 = (h0 * wg.dh) / wg.oh, jd1 = ((h0 + 1) * wg.dh) / wg.oh;
  int id0 = (w0 * wg.dw) / wg.ow, id1 = ((w0 + 1) * wg.dw) / wg.ow;
  float v00 = fmaxf(base[jd0 * wg.dw + id0], 0.f);
  float v01 = fmaxf(base[jd0 * wg.dw + id1], 0.f);
  float v10 = fmaxf(base[jd1 * wg.dw + id0], 0.f);
  float v11 = fmaxf(base[jd1 * wg.dw + id1], 0.f);
  float best = v00; int barg = 0;
  if (v01 > best) { best = v01; barg = 1; }
  if (v10 > best) { best = v10; barg = 2; }
  if (v11 > best) { best = v11; barg = 3; }
  int prg = (wg.to >> 1) + pr, pcg = (wg.lo >> 1) + pc;
  int out_i = (nc * 112 + prg) * 112 + pcg;
  vals[out_i] = best;
  int hh = 2 * prg + (barg >> 1), ww_ = 2 * pcg + (barg & 1);
  idxo[out_i] = (float)(hh * 224 + ww_);
}

extern "C" void kernel_launch(void* const* d_in, const int* in_sizes, int n_in,
                              void* d_out, int out_size, void* d_ws, size_t ws_size,
                              hipStream_t stream) {
  (void)in_sizes; (void)n_in; (void)out_size; (void)ws_size;
  const float* f = (const float*)d_in[0];
  const float* b = (const float*)d_in[1];
  const float* wfb = (const float*)d_in[2];
  const float* wconv = (const float*)d_in[3];
  float* ws = (float*)d_ws;

  float* xbuf = ws;                                    // region A: 51,380,224 floats
  float* vtmp = ws + XELEMS;                           // region B: vtot*1024 floats
  float* wt = ws + XELEMS + (size_t)GEO.vtot * 1024;   // 200,704 floats (dead; layout kept)
  float* wfbT = wt + 200704;                           // 8,192 floats
  unsigned* wbp = (unsigned*)(wfbT + 8192);            // 100,352 uints (bf16 B-fragments)
  float* dsb = xbuf;                                   // reuse region A (x dead after vresize)
  float* cwb = vtmp;                                   // reuse region B (vtmp dead after hresize)
  float* vals = (float*)d_out;
  float* idxo = (float*)d_out + POOL_N;

  k_wtr<<<816, 256, 0, stream>>>(wconv, wfb, wt, wfbT);
  k_wpack<<<WB2_UINTS / 256, 256, 0, stream>>>(wconv, wbp);
  k_pointwise<<<802816 / 256, 256, 0, stream>>>(f, b, wfbT, xbuf);
  k_vresize<<<GEO.jtot * 16, 256, 0, stream>>>(xbuf, vtmp);
  k_hresize<<<GEO.jtot * 16, 256, 0, stream>>>(vtmp, dsb);
  k_conv_mfma<<<GEO.btot, 256, 0, stream>>>(dsb, (const uint4*)wbp, cwb);
  k_pool<<<(GEO.ptot * 1024) / 256, 256, 0, stream>>>(cwb, vals, idxo);
}